// Round 4
// baseline (1094.397 us; speedup 1.0000x reference)
//
#include <hip/hip_runtime.h>

// Problem constants (fixed by the reference)
#define N_NODES 100000
#define N_EDGES 3200000
#define F_IN 32
#define F_EDGE 16
#define H 27
#define PAD 32            // node-feature row stride (128 B, line-aligned)
#define NB_NODES 391      // ceil(N/256)
#define NBUCK 391         // destination buckets of 256 nodes (col>>8)
#define BCAP 9216         // per-bucket capacity: lambda=8192, +11 sigma
#define CHUNK 12500       // edges per k_bin block; 256 * 12500 == E exactly

// ---------------------------------------------------------------------------
// cursor[b] = b * BCAP  (append cursors for the binned edge array)
// ---------------------------------------------------------------------------
__global__ __launch_bounds__(256) void k_initcur(int* __restrict__ cursor) {
    int i = blockIdx.x * 256 + threadIdx.x;
    if (i < NBUCK) cursor[i] = i * BCAP;
}

// ---------------------------------------------------------------------------
// One-pass binning: edges -> bucket-grouped array, coalesced segment writes.
// Record = (row << 8) | (col & 255); bucket = col >> 8.
// ---------------------------------------------------------------------------
__global__ __launch_bounds__(1024) void k_bin(const int* __restrict__ ei,
                                              int* __restrict__ cursor,
                                              int* __restrict__ binned) {
    __shared__ int stage[CHUNK];        // 50000 B
    __shared__ int hist[NBUCK];
    __shared__ int bstart[NBUCK];
    __shared__ int gbase[NBUCK];
    __shared__ int scanbuf[512];
    int tid = threadIdx.x;
    long long cs = (long long)blockIdx.x * CHUNK;

    for (int i = tid; i < NBUCK; i += 1024) hist[i] = 0;
    __syncthreads();

    int pk[13], bk[13], rk[13];
#pragma unroll
    for (int i = 0; i < 13; i++) {
        int j = tid + i * 1024;
        bk[i] = -1;
        if (j < CHUNK) {
            int e = (int)(cs + j);
            int r = ei[e];
            int c = ei[N_EDGES + e];
            int b = c >> 8;
            pk[i] = (r << 8) | (c & 255);
            bk[i] = b;
            rk[i] = atomicAdd(&hist[b], 1);   // rank within (chunk, bucket)
        }
    }
    __syncthreads();

    // exclusive scan of hist -> bstart (Hillis-Steele over 512, padded)
    if (tid < 512) scanbuf[tid] = (tid < NBUCK) ? hist[tid] : 0;
    __syncthreads();
    for (int off = 1; off < 512; off <<= 1) {
        int v = 0;
        if (tid < 512 && tid >= off) v = scanbuf[tid - off];
        __syncthreads();
        if (tid < 512) scanbuf[tid] += v;
        __syncthreads();
    }
    if (tid < NBUCK) {
        bstart[tid] = scanbuf[tid] - hist[tid];
        gbase[tid] = (hist[tid] > 0) ? atomicAdd(&cursor[tid], hist[tid]) : 0;
    }
    __syncthreads();

    // scatter into LDS stage, bucket-grouped
#pragma unroll
    for (int i = 0; i < 13; i++) {
        if (bk[i] >= 0) stage[bstart[bk[i]] + rk[i]] = pk[i];
    }
    __syncthreads();

    // coalesced drain: bucket of slot j via binary search on bstart
    for (int j = tid; j < CHUNK; j += 1024) {
        int lo = 0, hi = NBUCK - 1;
        while (lo < hi) {
            int mid = (lo + hi + 1) >> 1;
            if (bstart[mid] <= j) lo = mid; else hi = mid - 1;
        }
        binned[gbase[lo] + (j - bstart[lo])] = stage[j];
    }
}

// ---------------------------------------------------------------------------
// Degrees from bins (LDS histogram) -> dinv[n] = rsqrt(1 + indegree)
// ---------------------------------------------------------------------------
__global__ __launch_bounds__(256) void k_degdinv(const int* __restrict__ cursor,
                                                 const int* __restrict__ binned,
                                                 float* __restrict__ dinv) {
    __shared__ int deg[256];
    int b = blockIdx.x, tid = threadIdx.x;
    deg[tid] = 0;
    __syncthreads();
    int base = b * BCAP;
    int cnt = cursor[b] - base;
    for (int i = tid; i < cnt; i += 256)
        atomicAdd(&deg[binned[base + i] & 255], 1);
    __syncthreads();
    int n = b * 256 + tid;
    if (n < N_NODES) dinv[n] = rsqrtf((float)(deg[tid] + 1));
}

// ---------------------------------------------------------------------------
// Layer-1 pre: g1[n] = (x[n] @ W1) * dinv[n]  (row stride PAD)
// ---------------------------------------------------------------------------
__global__ __launch_bounds__(256) void k_l1pre(const float* __restrict__ x,
                                               const float* __restrict__ W1,
                                               const float* __restrict__ dinv,
                                               float* __restrict__ bufA) {
    __shared__ float w[F_IN * H];
    for (int i = threadIdx.x; i < F_IN * H; i += 256) w[i] = W1[i];
    __syncthreads();
    int n = blockIdx.x * 256 + threadIdx.x;
    if (n >= N_NODES) return;

    float xv[F_IN];
    const float4* xp = (const float4*)(x + (long long)n * F_IN);
#pragma unroll
    for (int j = 0; j < F_IN / 4; j++) {
        float4 v = xp[j];
        xv[4 * j] = v.x; xv[4 * j + 1] = v.y; xv[4 * j + 2] = v.z; xv[4 * j + 3] = v.w;
    }
    float di = dinv[n];
    long long base = (long long)n * PAD;
#pragma unroll
    for (int j = 0; j < H; j++) {
        float acc = 0.f;
#pragma unroll
        for (int k = 0; k < F_IN; k++) acc += xv[k] * w[k * H + j];
        bufA[base + j] = acc * di;
    }
}

// ---------------------------------------------------------------------------
// Layer-1 aggregate from bins: per-bucket LDS tile (256 nodes x 27 feats),
// gather g1[row], ds_add_f32 into tile, coalesced writeout with self-loop.
// 1024 threads = 32 groups x 32 lanes (lane = feature).
// ---------------------------------------------------------------------------
__global__ __launch_bounds__(1024) void k_agg27(const int* __restrict__ cursor,
                                                const int* __restrict__ binned,
                                                const float* __restrict__ bufA,
                                                float* __restrict__ bufB) {
    __shared__ float acc[256 * 28];   // 28 stride: lanes 0..26 hit distinct banks
    int tid = threadIdx.x;
    for (int i = tid; i < 256 * 28; i += 1024) acc[i] = 0.f;
    int b = blockIdx.x;
    int base = b * BCAP;
    int cnt = cursor[b] - base;
    __syncthreads();

    int grp = tid >> 5, lane = tid & 31;
    for (int i0 = grp * 4; i0 < cnt; i0 += 128) {
        int p0, p1 = -1, p2 = -1, p3 = -1;
        int m = cnt - i0;
        if (m >= 4) {
            int4 q = *(const int4*)&binned[base + i0];
            p0 = q.x; p1 = q.y; p2 = q.z; p3 = q.w;
        } else {
            p0 = binned[base + i0];
            if (m > 1) p1 = binned[base + i0 + 1];
            if (m > 2) p2 = binned[base + i0 + 2];
        }
        if (lane < 27) {
            float v0 = bufA[(long long)(p0 >> 8) * PAD + lane];
            float v1 = (p1 >= 0) ? bufA[(long long)(p1 >> 8) * PAD + lane] : 0.f;
            float v2 = (p2 >= 0) ? bufA[(long long)(p2 >> 8) * PAD + lane] : 0.f;
            float v3 = (p3 >= 0) ? bufA[(long long)(p3 >> 8) * PAD + lane] : 0.f;
            atomicAdd(&acc[(p0 & 255) * 28 + lane], v0);
            if (p1 >= 0) atomicAdd(&acc[(p1 & 255) * 28 + lane], v1);
            if (p2 >= 0) atomicAdd(&acc[(p2 & 255) * 28 + lane], v2);
            if (p3 >= 0) atomicAdd(&acc[(p3 & 255) * 28 + lane], v3);
        }
    }
    __syncthreads();

#pragma unroll
    for (int pass = 0; pass < 8; pass++) {
        int row = pass * 32 + grp;
        int n = b * 256 + row;
        if (lane < 27 && n < N_NODES)
            bufB[(long long)n * PAD + lane] =
                acc[row * 28 + lane] + bufA[(long long)n * PAD + lane];  // + self loop
    }
}

// ---------------------------------------------------------------------------
// Layer-1 post + layer-2 GEMM + head collapse:
//   o1 = relu(b1 + dinv*agg); g2 = (o1@W2)*dinv
//   s01[n] = (g2 . fcw[0:27], g2 . fcw[27:54])
// ---------------------------------------------------------------------------
__global__ __launch_bounds__(256) void k_l1post(const float* __restrict__ W2,
                                                const float* __restrict__ b1,
                                                const float* __restrict__ fcw,
                                                const float* __restrict__ dinv,
                                                const float* __restrict__ bufB,
                                                float2* __restrict__ s01) {
    __shared__ float w[H * H];
    __shared__ float bs[H];
    __shared__ float f0[H], f1[H];
    for (int i = threadIdx.x; i < H * H; i += 256) w[i] = W2[i];
    if (threadIdx.x < H) {
        bs[threadIdx.x] = b1[threadIdx.x];
        f0[threadIdx.x] = fcw[threadIdx.x];
        f1[threadIdx.x] = fcw[H + threadIdx.x];
    }
    __syncthreads();
    int n = blockIdx.x * 256 + threadIdx.x;
    if (n >= N_NODES) return;

    float di = dinv[n];
    long long base = (long long)n * PAD;
    float o1[H];
#pragma unroll
    for (int k = 0; k < H; k++) {
        float v = bs[k] + di * bufB[base + k];
        o1[k] = v > 0.f ? v : 0.f;
    }
    float r0 = 0.f, r1 = 0.f;
#pragma unroll
    for (int j = 0; j < H; j++) {
        float g = 0.f;
#pragma unroll
        for (int k = 0; k < H; k++) g += o1[k] * w[k * H + j];
        g *= di;
        r0 += g * f0[j];
        r1 += g * f1[j];
    }
    s01[n] = make_float2(r0, r1);
}

// ---------------------------------------------------------------------------
// Tiny prep: vbuf[0:27] = ew2 @ fcw[54:81]; vbuf[27] = fcb + eb2 . fcw[54:81];
//            vbuf[28] = b2 . fcw[0:27];     vbuf[29] = b2 . fcw[27:54]
// ---------------------------------------------------------------------------
__global__ void k_prep(const float* __restrict__ ew2,
                       const float* __restrict__ eb2,
                       const float* __restrict__ b2,
                       const float* __restrict__ fcw,
                       const float* __restrict__ fcb,
                       float* __restrict__ vbuf) {
    int k = threadIdx.x;
    if (k < H) {
        float acc = 0.f;
#pragma unroll
        for (int j = 0; j < H; j++) acc += ew2[k * H + j] * fcw[2 * H + j];
        vbuf[k] = acc;
    } else if (k == H) {
        float acc = fcb[0];
#pragma unroll
        for (int j = 0; j < H; j++) acc += eb2[j] * fcw[2 * H + j];
        vbuf[H] = acc;
    } else if (k == H + 1) {
        float acc = 0.f;
#pragma unroll
        for (int j = 0; j < H; j++) acc += b2[j] * fcw[j];
        vbuf[H + 1] = acc;
    } else if (k == H + 2) {
        float acc = 0.f;
#pragma unroll
        for (int j = 0; j < H; j++) acc += b2[j] * fcw[H + j];
        vbuf[H + 2] = acc;
    }
}

// ---------------------------------------------------------------------------
// Layer-2 scalar aggregate from bins + head:
//   pr[n] = (b2.f0) + dinv*(s0[n] + sum s0[src]);  pc likewise
// s01 table (800 KB) is per-XCD-L2 resident -> cheap gathers.
// ---------------------------------------------------------------------------
__global__ __launch_bounds__(256) void k_agg2(const int* __restrict__ cursor,
                                              const int* __restrict__ binned,
                                              const float2* __restrict__ s01,
                                              const float* __restrict__ dinv,
                                              const float* __restrict__ vbuf,
                                              float* __restrict__ pr,
                                              float* __restrict__ pc) {
    __shared__ float a0[256], a1[256];
    int b = blockIdx.x, tid = threadIdx.x;
    a0[tid] = 0.f; a1[tid] = 0.f;
    __syncthreads();
    int base = b * BCAP;
    int cnt = cursor[b] - base;
    for (int i = tid; i < cnt; i += 256) {
        int p = binned[base + i];
        float2 s = s01[p >> 8];
        int cl = p & 255;
        atomicAdd(&a0[cl], s.x);
        atomicAdd(&a1[cl], s.y);
    }
    __syncthreads();
    int n = b * 256 + tid;
    if (n < N_NODES) {
        float2 ss = s01[n];
        float di = dinv[n];
        pr[n] = vbuf[H + 1] + di * (a0[tid] + ss.x);
        pc[n] = vbuf[H + 2] + di * (a1[tid] + ss.y);
    }
}

// ---------------------------------------------------------------------------
// Edge head, collapsed:
//   out[e] = c0 + sum_k relu(b1e[k] + ea[e].w1[:,k]) * v[k] + pr[row] + pc[col]
// ---------------------------------------------------------------------------
__global__ __launch_bounds__(256) void k_edge_final(const int* __restrict__ ei,
                                                    const float* __restrict__ ea,
                                                    const float* __restrict__ ew1,
                                                    const float* __restrict__ eb1,
                                                    const float* __restrict__ vbuf,
                                                    const float* __restrict__ pr,
                                                    const float* __restrict__ pc,
                                                    float* __restrict__ out) {
    __shared__ float w1t[H * F_EDGE];  // transposed: [k][m], column k contiguous
    __shared__ float b1s[H];
    __shared__ float vs[H];
    __shared__ float c0s;
    for (int i = threadIdx.x; i < H * F_EDGE; i += 256) {
        int k = i >> 4, m = i & 15;
        w1t[i] = ew1[m * H + k];
    }
    if (threadIdx.x < H) { b1s[threadIdx.x] = eb1[threadIdx.x]; vs[threadIdx.x] = vbuf[threadIdx.x]; }
    if (threadIdx.x == 0) c0s = vbuf[H];
    __syncthreads();

    long long t = (long long)blockIdx.x * 256 + threadIdx.x;
    long long e0 = t * 4;
    if (e0 >= N_EDGES) return;

    float a[4][F_EDGE];
#pragma unroll
    for (int i = 0; i < 4; i++) {
        const float4* p = (const float4*)(ea + (e0 + i) * F_EDGE);
#pragma unroll
        for (int j = 0; j < F_EDGE / 4; j++) {
            float4 v = p[j];
            a[i][4 * j] = v.x; a[i][4 * j + 1] = v.y; a[i][4 * j + 2] = v.z; a[i][4 * j + 3] = v.w;
        }
    }

    float c0 = c0s;
    float acc[4] = {c0, c0, c0, c0};
    const float4* w1v = (const float4*)w1t;
#pragma unroll
    for (int k = 0; k < H; k++) {
        float4 wa = w1v[k * 4 + 0];
        float4 wb = w1v[k * 4 + 1];
        float4 wc = w1v[k * 4 + 2];
        float4 wd = w1v[k * 4 + 3];
        float bk = b1s[k];
        float vk = vs[k];
#pragma unroll
        for (int i = 0; i < 4; i++) {
            float s = bk;
            s += a[i][0] * wa.x + a[i][1] * wa.y + a[i][2] * wa.z + a[i][3] * wa.w;
            s += a[i][4] * wb.x + a[i][5] * wb.y + a[i][6] * wb.z + a[i][7] * wb.w;
            s += a[i][8] * wc.x + a[i][9] * wc.y + a[i][10] * wc.z + a[i][11] * wc.w;
            s += a[i][12] * wd.x + a[i][13] * wd.y + a[i][14] * wd.z + a[i][15] * wd.w;
            acc[i] += (s > 0.f ? s : 0.f) * vk;
        }
    }

    float res[4];
#pragma unroll
    for (int i = 0; i < 4; i++) {
        int r = ei[e0 + i];
        int c = ei[N_EDGES + e0 + i];
        res[i] = acc[i] + pr[r] + pc[c];
    }
    *(float4*)(out + e0) = *(float4*)res;
}

// ---------------------------------------------------------------------------
extern "C" void kernel_launch(void* const* d_in, const int* in_sizes, int n_in,
                              void* d_out, int out_size, void* d_ws, size_t ws_size,
                              hipStream_t stream) {
    const float* x   = (const float*)d_in[0];
    const int*   ei  = (const int*)d_in[1];
    const float* ea  = (const float*)d_in[2];
    const float* W1  = (const float*)d_in[3];
    const float* b1  = (const float*)d_in[4];
    const float* W2  = (const float*)d_in[5];
    const float* b2  = (const float*)d_in[6];
    const float* ew1 = (const float*)d_in[7];
    const float* eb1 = (const float*)d_in[8];
    const float* ew2 = (const float*)d_in[9];
    const float* eb2 = (const float*)d_in[10];
    const float* fcw = (const float*)d_in[11];
    const float* fcb = (const float*)d_in[12];
    float* out = (float*)d_out;

    // Workspace layout (all offsets in elements, 16B-aligned by construction)
    int* cursor  = (int*)d_ws;                            // NBUCK (pad to 1024)
    int* binned  = cursor + 1024;                         // NBUCK*BCAP = 3,603,456
    float* dinv  = (float*)(binned + (size_t)NBUCK * BCAP);  // N
    float* bufA  = dinv + N_NODES;                        // N*PAD
    float* bufB  = bufA + (size_t)N_NODES * PAD;          // N*PAD
    float2* s01  = (float2*)(bufB + (size_t)N_NODES * PAD); // N float2
    float* pr    = (float*)(s01 + N_NODES);               // N
    float* pc    = pr + N_NODES;                          // N
    float* vbuf  = pc + N_NODES;                          // 32

    const int nb_e4 = N_EDGES / 4 / 256;   // 3125 exact

    // Binning (replaces CSR count/scan/fill)
    k_initcur<<<2, 256, 0, stream>>>(cursor);
    k_bin<<<256, 1024, 0, stream>>>(ei, cursor, binned);
    k_degdinv<<<NBUCK, 256, 0, stream>>>(cursor, binned, dinv);
    k_prep<<<1, 64, 0, stream>>>(ew2, eb2, b2, fcw, fcb, vbuf);

    // Layer 1
    k_l1pre<<<NB_NODES, 256, 0, stream>>>(x, W1, dinv, bufA);
    k_agg27<<<NBUCK, 1024, 0, stream>>>(cursor, binned, bufA, bufB);

    // Layer 2 collapsed to per-node scalars
    k_l1post<<<NB_NODES, 256, 0, stream>>>(W2, b1, fcw, dinv, bufB, s01);
    k_agg2<<<NBUCK, 256, 0, stream>>>(cursor, binned, s01, dinv, vbuf, pr, pc);

    // Edge head
    k_edge_final<<<nb_e4, 256, 0, stream>>>(ei, ea, ew1, eb1, vbuf, pr, pc, out);
}

// Round 5
// 615.194 us; speedup vs baseline: 1.7789x; 1.7789x over previous
//
#include <hip/hip_runtime.h>

// Problem constants (fixed by the reference)
#define N_NODES 100000
#define N_EDGES 3200000
#define F_IN 32
#define F_EDGE 16
#define H 27
#define PAD 32            // node-feature row stride (128 B, line-aligned)
#define NB_NODES 391      // ceil(N/256)
#define NBUCK 391         // destination buckets of 256 nodes (col>>8)
#define BCAP 9216         // per-bucket capacity: mean 8184, +11 sigma
#define CHUNK 12500       // edges per k_bin block; 256 * 12500 == E exactly

// ---------------------------------------------------------------------------
// cursor[b] = b * BCAP  (append cursors for the binned edge array)
// ---------------------------------------------------------------------------
__global__ __launch_bounds__(256) void k_initcur(int* __restrict__ cursor) {
    int i = blockIdx.x * 256 + threadIdx.x;
    if (i < NBUCK) cursor[i] = i * BCAP;
}

// ---------------------------------------------------------------------------
// One-pass binning: edges -> bucket-grouped array, coalesced segment writes.
// Record = (row << 8) | (col & 255); bucket = col >> 8.  (validated round 4)
// ---------------------------------------------------------------------------
__global__ __launch_bounds__(1024) void k_bin(const int* __restrict__ ei,
                                              int* __restrict__ cursor,
                                              int* __restrict__ binned) {
    __shared__ int stage[CHUNK];        // 50000 B
    __shared__ int hist[NBUCK];
    __shared__ int bstart[NBUCK];
    __shared__ int gbase[NBUCK];
    __shared__ int scanbuf[512];
    int tid = threadIdx.x;
    long long cs = (long long)blockIdx.x * CHUNK;

    for (int i = tid; i < NBUCK; i += 1024) hist[i] = 0;
    __syncthreads();

    int pk[13], bk[13], rk[13];
#pragma unroll
    for (int i = 0; i < 13; i++) {
        int j = tid + i * 1024;
        bk[i] = -1;
        if (j < CHUNK) {
            int e = (int)(cs + j);
            int r = ei[e];
            int c = ei[N_EDGES + e];
            int b = c >> 8;
            pk[i] = (r << 8) | (c & 255);
            bk[i] = b;
            rk[i] = atomicAdd(&hist[b], 1);   // rank within (chunk, bucket)
        }
    }
    __syncthreads();

    // exclusive scan of hist -> bstart (Hillis-Steele over 512, padded)
    if (tid < 512) scanbuf[tid] = (tid < NBUCK) ? hist[tid] : 0;
    __syncthreads();
    for (int off = 1; off < 512; off <<= 1) {
        int v = 0;
        if (tid < 512 && tid >= off) v = scanbuf[tid - off];
        __syncthreads();
        if (tid < 512) scanbuf[tid] += v;
        __syncthreads();
    }
    if (tid < NBUCK) {
        bstart[tid] = scanbuf[tid] - hist[tid];
        gbase[tid] = (hist[tid] > 0) ? atomicAdd(&cursor[tid], hist[tid]) : 0;
    }
    __syncthreads();

    // scatter into LDS stage, bucket-grouped
#pragma unroll
    for (int i = 0; i < 13; i++) {
        if (bk[i] >= 0) stage[bstart[bk[i]] + rk[i]] = pk[i];
    }
    __syncthreads();

    // coalesced drain: bucket of slot j via binary search on bstart
    for (int j = tid; j < CHUNK; j += 1024) {
        int lo = 0, hi = NBUCK - 1;
        while (lo < hi) {
            int mid = (lo + hi + 1) >> 1;
            if (bstart[mid] <= j) lo = mid; else hi = mid - 1;
        }
        binned[gbase[lo] + (j - bstart[lo])] = stage[j];
    }
}

// ---------------------------------------------------------------------------
// Bucket-count exclusive scan -> bbase; also ptr[N] = E.
// ---------------------------------------------------------------------------
__global__ __launch_bounds__(512) void k_bscan(const int* __restrict__ cursor,
                                               int* __restrict__ bbase,
                                               int* __restrict__ ptr) {
    __shared__ int sb[512];
    int tid = threadIdx.x;
    int cnt = (tid < NBUCK) ? (cursor[tid] - tid * BCAP) : 0;
    sb[tid] = cnt;
    __syncthreads();
    for (int off = 1; off < 512; off <<= 1) {
        int t = (tid >= off) ? sb[tid - off] : 0;
        __syncthreads();
        sb[tid] += t;
        __syncthreads();
    }
    if (tid < NBUCK) bbase[tid] = sb[tid] - cnt;
    if (tid == NBUCK - 1) ptr[N_NODES] = sb[tid];   // == N_EDGES
}

// ---------------------------------------------------------------------------
// Per-bucket counting sort: binned records -> csr (rows grouped by dest node),
// ptr[n], dinv[n].  All writes coalesced; LDS histogram + scan + stage.
// ---------------------------------------------------------------------------
__global__ __launch_bounds__(256) void k_bin2(const int* __restrict__ cursor,
                                              const int* __restrict__ binned,
                                              const int* __restrict__ bbase,
                                              int* __restrict__ ptr,
                                              int* __restrict__ csr,
                                              float* __restrict__ dinv) {
    __shared__ int hist[256];
    __shared__ int offs[256];
    __shared__ int stage[BCAP];     // 36 KB
    int b = blockIdx.x, tid = threadIdx.x;
    hist[tid] = 0;
    __syncthreads();
    int base = b * BCAP;
    int cnt = cursor[b] - base;
    int gb = bbase[b];

    int recs[36], rks[36];
#pragma unroll
    for (int i = 0; i < 36; i++) {
        int j = tid + i * 256;
        recs[i] = -1;
        if (j < cnt) {
            int rec = binned[base + j];
            recs[i] = rec;
            rks[i] = atomicAdd(&hist[rec & 255], 1);
        }
    }
    __syncthreads();

    int v = hist[tid];
    offs[tid] = v;
    __syncthreads();
    for (int off = 1; off < 256; off <<= 1) {    // inclusive scan
        int t = (tid >= off) ? offs[tid - off] : 0;
        __syncthreads();
        offs[tid] += t;
        __syncthreads();
    }
    int excl = offs[tid] - v;
    int n = b * 256 + tid;
    if (n < N_NODES) {
        ptr[n] = gb + excl;
        dinv[n] = rsqrtf((float)(v + 1));
    }
    __syncthreads();
    offs[tid] = excl;
    __syncthreads();

#pragma unroll
    for (int i = 0; i < 36; i++) {
        if (recs[i] >= 0) stage[offs[recs[i] & 255] + rks[i]] = recs[i] >> 8;
    }
    __syncthreads();
    for (int j = tid; j < cnt; j += 256) csr[gb + j] = stage[j];
}

// ---------------------------------------------------------------------------
// Layer-1 pre: g1[n] = (x[n] @ W1) * dinv[n]  (row stride PAD)
// ---------------------------------------------------------------------------
__global__ __launch_bounds__(256) void k_l1pre(const float* __restrict__ x,
                                               const float* __restrict__ W1,
                                               const float* __restrict__ dinv,
                                               float* __restrict__ bufA) {
    __shared__ float w[F_IN * H];
    for (int i = threadIdx.x; i < F_IN * H; i += 256) w[i] = W1[i];
    __syncthreads();
    int n = blockIdx.x * 256 + threadIdx.x;
    if (n >= N_NODES) return;

    float xv[F_IN];
    const float4* xp = (const float4*)(x + (long long)n * F_IN);
#pragma unroll
    for (int j = 0; j < F_IN / 4; j++) {
        float4 v = xp[j];
        xv[4 * j] = v.x; xv[4 * j + 1] = v.y; xv[4 * j + 2] = v.z; xv[4 * j + 3] = v.w;
    }
    float di = dinv[n];
    long long base = (long long)n * PAD;
#pragma unroll
    for (int j = 0; j < H; j++) {
        float acc = 0.f;
#pragma unroll
        for (int k = 0; k < F_IN; k++) acc += xv[k] * w[k * H + j];
        bufA[base + j] = acc * di;
    }
}

// ---------------------------------------------------------------------------
// Fused layer-1 aggregate (pull) + layer-1 post + layer-2 GEMM + head collapse:
//   agg = g1[n] + sum g1[src]; o1 = relu(b1 + dinv*agg) (lane-distributed)
//   g2_j = (sum_k o1_k W2[k][j]) * dinv;  s01[n] = (g2.f0, g2.f1)
// 32 lanes per node; lane = feature.
// ---------------------------------------------------------------------------
__global__ __launch_bounds__(256) void k_gather_post(const int* __restrict__ ptr,
                                                     const int* __restrict__ csr,
                                                     const float* __restrict__ bufA,
                                                     const float* __restrict__ W2,
                                                     const float* __restrict__ b1,
                                                     const float* __restrict__ fcw,
                                                     const float* __restrict__ dinv,
                                                     float2* __restrict__ s01) {
    __shared__ float w[H * H];
    __shared__ float bs[H], f0[H], f1[H];
    for (int i = threadIdx.x; i < H * H; i += 256) w[i] = W2[i];
    if (threadIdx.x < H) {
        bs[threadIdx.x] = b1[threadIdx.x];
        f0[threadIdx.x] = fcw[threadIdx.x];
        f1[threadIdx.x] = fcw[H + threadIdx.x];
    }
    __syncthreads();

    int g = blockIdx.x * 256 + threadIdx.x;
    int n = g >> 5;
    int lane = g & 31;
    if (n >= N_NODES) return;
    int p0 = ptr[n], p1 = ptr[n + 1];

    float acc = (lane < H) ? bufA[(long long)n * PAD + lane] : 0.f;  // self loop
    int i = p0;
    while (i < p1) {
        int m = p1 - i; if (m > 32) m = 32;
        int idx = (lane < m) ? csr[i + lane] : 0;   // one coalesced batch load
#pragma unroll 4
        for (int j = 0; j < m; j++) {
            int r = __shfl(idx, j, 32);
            acc += bufA[(long long)r * PAD + lane];  // 2 cache lines per row
        }
        i += m;
    }

    // layer-1 epilogue + layer-2 GEMM, in-register across the 32-lane group
    float di = dinv[n];
    float o1 = 0.f;
    if (lane < H) {
        float t = bs[lane] + di * acc;
        o1 = t > 0.f ? t : 0.f;
    }
    float gj = 0.f;
#pragma unroll
    for (int k = 0; k < H; k++) {
        float ok = __shfl(o1, k, 32);
        if (lane < H) gj += ok * w[k * H + lane];
    }
    float t0 = 0.f, t1 = 0.f;
    if (lane < H) {
        float gd = gj * di;
        t0 = gd * f0[lane];
        t1 = gd * f1[lane];
    }
#pragma unroll
    for (int off = 16; off > 0; off >>= 1) {
        t0 += __shfl_xor(t0, off, 32);
        t1 += __shfl_xor(t1, off, 32);
    }
    if (lane == 0) s01[n] = make_float2(t0, t1);
}

// ---------------------------------------------------------------------------
// Tiny prep: vbuf[0:27] = ew2 @ fcw[54:81]; vbuf[27] = fcb + eb2 . fcw[54:81];
//            vbuf[28] = b2 . fcw[0:27];     vbuf[29] = b2 . fcw[27:54]
// ---------------------------------------------------------------------------
__global__ void k_prep(const float* __restrict__ ew2,
                       const float* __restrict__ eb2,
                       const float* __restrict__ b2,
                       const float* __restrict__ fcw,
                       const float* __restrict__ fcb,
                       float* __restrict__ vbuf) {
    int k = threadIdx.x;
    if (k < H) {
        float acc = 0.f;
#pragma unroll
        for (int j = 0; j < H; j++) acc += ew2[k * H + j] * fcw[2 * H + j];
        vbuf[k] = acc;
    } else if (k == H) {
        float acc = fcb[0];
#pragma unroll
        for (int j = 0; j < H; j++) acc += eb2[j] * fcw[2 * H + j];
        vbuf[H] = acc;
    } else if (k == H + 1) {
        float acc = 0.f;
#pragma unroll
        for (int j = 0; j < H; j++) acc += b2[j] * fcw[j];
        vbuf[H + 1] = acc;
    } else if (k == H + 2) {
        float acc = 0.f;
#pragma unroll
        for (int j = 0; j < H; j++) acc += b2[j] * fcw[H + j];
        vbuf[H + 2] = acc;
    }
}

// ---------------------------------------------------------------------------
// Layer-2 scalar aggregate (pull) + head:
//   pr[n] = (b2.f0) + dinv*(s0[n] + sum s0[src]);  pc likewise with s1
// ---------------------------------------------------------------------------
__global__ __launch_bounds__(256) void k_pull2(const int* __restrict__ ptr,
                                               const int* __restrict__ csr,
                                               const float2* __restrict__ s01,
                                               const float* __restrict__ dinv,
                                               const float* __restrict__ vbuf,
                                               float* __restrict__ pr,
                                               float* __restrict__ pc) {
    int g = blockIdx.x * 256 + threadIdx.x;
    int n = g >> 5;
    int lane = g & 31;
    if (n >= N_NODES) return;
    int p0 = ptr[n], p1 = ptr[n + 1];

    float a0 = 0.f, a1 = 0.f;
    for (int i = p0 + lane; i < p1; i += 32) {
        float2 s = s01[csr[i]];
        a0 += s.x;
        a1 += s.y;
    }
#pragma unroll
    for (int off = 16; off > 0; off >>= 1) {
        a0 += __shfl_down(a0, off, 32);
        a1 += __shfl_down(a1, off, 32);
    }
    if (lane == 0) {
        float2 ss = s01[n];
        float di = dinv[n];
        pr[n] = vbuf[H + 1] + di * (a0 + ss.x);
        pc[n] = vbuf[H + 2] + di * (a1 + ss.y);
    }
}

// ---------------------------------------------------------------------------
// Edge head, collapsed:
//   out[e] = c0 + sum_k relu(b1e[k] + ea[e].w1[:,k]) * v[k] + pr[row] + pc[col]
// ---------------------------------------------------------------------------
__global__ __launch_bounds__(256) void k_edge_final(const int* __restrict__ ei,
                                                    const float* __restrict__ ea,
                                                    const float* __restrict__ ew1,
                                                    const float* __restrict__ eb1,
                                                    const float* __restrict__ vbuf,
                                                    const float* __restrict__ pr,
                                                    const float* __restrict__ pc,
                                                    float* __restrict__ out) {
    __shared__ float w1t[H * F_EDGE];  // transposed: [k][m], column k contiguous
    __shared__ float b1s[H];
    __shared__ float vs[H];
    __shared__ float c0s;
    for (int i = threadIdx.x; i < H * F_EDGE; i += 256) {
        int k = i >> 4, m = i & 15;
        w1t[i] = ew1[m * H + k];
    }
    if (threadIdx.x < H) { b1s[threadIdx.x] = eb1[threadIdx.x]; vs[threadIdx.x] = vbuf[threadIdx.x]; }
    if (threadIdx.x == 0) c0s = vbuf[H];
    __syncthreads();

    long long t = (long long)blockIdx.x * 256 + threadIdx.x;
    long long e0 = t * 4;
    if (e0 >= N_EDGES) return;

    float a[4][F_EDGE];
#pragma unroll
    for (int i = 0; i < 4; i++) {
        const float4* p = (const float4*)(ea + (e0 + i) * F_EDGE);
#pragma unroll
        for (int j = 0; j < F_EDGE / 4; j++) {
            float4 v = p[j];
            a[i][4 * j] = v.x; a[i][4 * j + 1] = v.y; a[i][4 * j + 2] = v.z; a[i][4 * j + 3] = v.w;
        }
    }

    float c0 = c0s;
    float acc[4] = {c0, c0, c0, c0};
    const float4* w1v = (const float4*)w1t;
#pragma unroll
    for (int k = 0; k < H; k++) {
        float4 wa = w1v[k * 4 + 0];
        float4 wb = w1v[k * 4 + 1];
        float4 wc = w1v[k * 4 + 2];
        float4 wd = w1v[k * 4 + 3];
        float bk = b1s[k];
        float vk = vs[k];
#pragma unroll
        for (int i = 0; i < 4; i++) {
            float s = bk;
            s += a[i][0] * wa.x + a[i][1] * wa.y + a[i][2] * wa.z + a[i][3] * wa.w;
            s += a[i][4] * wb.x + a[i][5] * wb.y + a[i][6] * wb.z + a[i][7] * wb.w;
            s += a[i][8] * wc.x + a[i][9] * wc.y + a[i][10] * wc.z + a[i][11] * wc.w;
            s += a[i][12] * wd.x + a[i][13] * wd.y + a[i][14] * wd.z + a[i][15] * wd.w;
            acc[i] += (s > 0.f ? s : 0.f) * vk;
        }
    }

    float res[4];
#pragma unroll
    for (int i = 0; i < 4; i++) {
        int r = ei[e0 + i];
        int c = ei[N_EDGES + e0 + i];
        res[i] = acc[i] + pr[r] + pc[c];
    }
    *(float4*)(out + e0) = *(float4*)res;
}

// ---------------------------------------------------------------------------
extern "C" void kernel_launch(void* const* d_in, const int* in_sizes, int n_in,
                              void* d_out, int out_size, void* d_ws, size_t ws_size,
                              hipStream_t stream) {
    const float* x   = (const float*)d_in[0];
    const int*   ei  = (const int*)d_in[1];
    const float* ea  = (const float*)d_in[2];
    const float* W1  = (const float*)d_in[3];
    const float* b1  = (const float*)d_in[4];
    const float* W2  = (const float*)d_in[5];
    const float* b2  = (const float*)d_in[6];
    const float* ew1 = (const float*)d_in[7];
    const float* eb1 = (const float*)d_in[8];
    const float* ew2 = (const float*)d_in[9];
    const float* eb2 = (const float*)d_in[10];
    const float* fcw = (const float*)d_in[11];
    const float* fcb = (const float*)d_in[12];
    float* out = (float*)d_out;

    // Workspace layout (elements)
    int* cursor  = (int*)d_ws;                               // 1024
    int* bbase   = cursor + 1024;                            // 512
    int* binned  = bbase + 512;                              // NBUCK*BCAP
    int* ptr     = binned + (size_t)NBUCK * BCAP;            // N+1 (pad 1024)
    int* csr     = ptr + N_NODES + 1024;                     // E
    float* dinv  = (float*)(csr + N_EDGES);                  // N
    float* bufA  = dinv + N_NODES;                           // N*PAD
    float2* s01  = (float2*)(bufA + (size_t)N_NODES * PAD);  // N float2
    float* pr    = (float*)(s01 + N_NODES);                  // N
    float* pc    = pr + N_NODES;                             // N
    float* vbuf  = pc + N_NODES;                             // 32

    const int nb_ng = (N_NODES * 32 + 255) / 256;  // 12500
    const int nb_e4 = N_EDGES / 4 / 256;           // 3125 exact

    // Build sorted-by-destination CSR via two-level binning (no fp atomics,
    // no random global scatter: all global writes coalesced)
    k_initcur<<<2, 256, 0, stream>>>(cursor);
    k_bin<<<256, 1024, 0, stream>>>(ei, cursor, binned);
    k_bscan<<<1, 512, 0, stream>>>(cursor, bbase, ptr);
    k_bin2<<<NBUCK, 256, 0, stream>>>(cursor, binned, bbase, ptr, csr, dinv);

    k_prep<<<1, 64, 0, stream>>>(ew2, eb2, b2, fcw, fcb, vbuf);

    // Layer 1 + fused layer-2 GEMM/head-collapse
    k_l1pre<<<NB_NODES, 256, 0, stream>>>(x, W1, dinv, bufA);
    k_gather_post<<<nb_ng, 256, 0, stream>>>(ptr, csr, bufA, W2, b1, fcw, dinv, s01);

    // Layer-2 scalar aggregate + per-node head
    k_pull2<<<nb_ng, 256, 0, stream>>>(ptr, csr, s01, dinv, vbuf, pr, pc);

    // Edge head
    k_edge_final<<<nb_e4, 256, 0, stream>>>(ei, ea, ew1, eb1, vbuf, pr, pc, out);
}